// Round 6
// baseline (694.051 us; speedup 1.0000x reference)
//
#include <hip/hip_runtime.h>
#include <hip/hip_bf16.h>
#include <math.h>

#define NODES 50000
#define FEAT 128
#define NB 196          // ceil(50000/256) buckets of 256 nodes
#define BCAP 12288      // per-bucket adj capacity (mean 8192, sd ~90)
#define NPH 6250        // nodes per src-phase slice (8 slices x 1.6 MB table)

typedef __attribute__((ext_vector_type(4))) float f32x4;
typedef __attribute__((ext_vector_type(8))) short short8;
union UV { uint4 u; short8 s; };

__device__ __forceinline__ unsigned bf16rne(float x) {
  unsigned u = __float_as_uint(x);
  return (u + 0x7FFFu + ((u >> 16) & 1u)) >> 16;  // RNE, result in low 16
}

// fused: cast x -> packed bf16 | pack 3 weight matrices | zero bcount/bcur/g
__global__ __launch_bounds__(256) void k_prep(
    const float* __restrict__ x, const float* __restrict__ W1,
    const float* __restrict__ W2, const float* __restrict__ W3,
    unsigned* __restrict__ h16, uint4* __restrict__ Wb1,
    uint4* __restrict__ Wb2, uint4* __restrict__ Wb3, int* __restrict__ zreg) {
  int b = blockIdx.x, t = threadIdx.x;
  if (b < 12500) {                       // cast: 12500*256 == NODES*64 exactly
    int i = b * 256 + t;
    float2 v = ((const float2*)x)[i];
    h16[i] = bf16rne(v.x) | (bf16rne(v.y) << 16);
  } else if (b < 12548) {                // wpack: 3 x 16 blocks
    int q = b - 12500;
    const float* __restrict__ W = (q < 16) ? W1 : (q < 32) ? W2 : W3;
    uint4* __restrict__ Wb = (q < 16) ? Wb1 : (q < 32) ? Wb2 : Wb3;
    int tid = (q & 15) * 256 + t;        // 0..4095
    int lane = tid & 63, nf = (tid >> 6) & 7, ks = tid >> 9;
    int kb = ks * 32 + (lane >> 4) * 8;
    int col = nf * 16 + (lane & 15);
    uint4 r;
    r.x = bf16rne(W[(kb + 0) * FEAT + col]) | (bf16rne(W[(kb + 1) * FEAT + col]) << 16);
    r.y = bf16rne(W[(kb + 2) * FEAT + col]) | (bf16rne(W[(kb + 3) * FEAT + col]) << 16);
    r.z = bf16rne(W[(kb + 4) * FEAT + col]) | (bf16rne(W[(kb + 5) * FEAT + col]) << 16);
    r.w = bf16rne(W[(kb + 6) * FEAT + col]) | (bf16rne(W[(kb + 7) * FEAT + col]) << 16);
    Wb[tid] = r;
  } else {                               // zero bcount|bcur|g : 8704 ints
    int i = (b - 12548) * 256 + t;
    if (i < 8704) zreg[i] = 0;
  }
}

// Pass A: coarse bucket histogram (bucket = node >> 8), LDS-aggregated
__global__ __launch_bounds__(256) void k_bcount(const int* __restrict__ src,
                                                const int* __restrict__ dst,
                                                int E, int* __restrict__ bcount) {
  __shared__ int cnt[NB];
  int t = threadIdx.x;
  for (int i = t; i < NB; i += 256) cnt[i] = 0;
  __syncthreads();
  int base = blockIdx.x * 4096;
  int nE = min(4096, E - base);
  for (int k = t; k < nE; k += 256) {
    int s = src[base + k], d = dst[base + k];
    atomicAdd(&cnt[d >> 8], 1);
    atomicAdd(&cnt[s >> 8], 1);
  }
  __syncthreads();
  for (int i = t; i < NB; i += 256)
    if (cnt[i]) atomicAdd(&bcount[i], cnt[i]);
}

// exclusive scan of NB bucket counts -> bbase[NB+1]
__global__ __launch_bounds__(256) void k_bscan(const int* __restrict__ bcount,
                                               int* __restrict__ bbase, int twoE) {
  __shared__ int sc[256];
  int t = threadIdx.x;
  int v = (t < NB) ? bcount[t] : 0;
  sc[t] = v;
  __syncthreads();
  for (int off = 1; off < 256; off <<= 1) {
    int u = (t >= off) ? sc[t - off] : 0;
    __syncthreads();
    sc[t] += u;
    __syncthreads();
  }
  if (t < NB) bbase[t] = sc[t] - v;
  if (t == 0) bbase[NB] = twoE;
}

// Pass B: bucket-sort (d,s) pairs via LDS staging, flush in contiguous runs
__global__ __launch_bounds__(256) void k_bin(const int* __restrict__ src,
                                             const int* __restrict__ dst, int E,
                                             const int* __restrict__ bbase,
                                             int* __restrict__ bcur,
                                             uint2* __restrict__ binned) {
  __shared__ uint2 stage[8192];
  __shared__ int cnt[NB];
  __shared__ int lbase[NB];
  __shared__ int gbase[NB];
  __shared__ int lcur[NB];
  __shared__ int sc[256];
  int t = threadIdx.x;
  for (int i = t; i < NB; i += 256) cnt[i] = 0;
  __syncthreads();
  int base = blockIdx.x * 4096;
  int nE = min(4096, E - base);
  for (int k = t; k < nE; k += 256) {
    int s = src[base + k], d = dst[base + k];
    atomicAdd(&cnt[d >> 8], 1);
    atomicAdd(&cnt[s >> 8], 1);
  }
  __syncthreads();
  int v = (t < NB) ? cnt[t] : 0;
  sc[t] = v;
  __syncthreads();
  for (int off = 1; off < 256; off <<= 1) {
    int u = (t >= off) ? sc[t - off] : 0;
    __syncthreads();
    sc[t] += u;
    __syncthreads();
  }
  if (t < NB) {
    lbase[t] = sc[t] - v;
    lcur[t] = sc[t] - v;
  }
  __syncthreads();
  int total = sc[255];
  for (int k = t; k < nE; k += 256) {
    int s = src[base + k], d = dst[base + k];
    int p1 = atomicAdd(&lcur[d >> 8], 1);
    stage[p1] = make_uint2((unsigned)d, (unsigned)s);
    int p2 = atomicAdd(&lcur[s >> 8], 1);
    stage[p2] = make_uint2((unsigned)s, (unsigned)d);
  }
  __syncthreads();
  if (t < NB && cnt[t] > 0) gbase[t] = bbase[t] + atomicAdd(&bcur[t], cnt[t]);
  __syncthreads();
  for (int k = t; k < total; k += 256) {
    uint2 p = stage[k];
    int b = p.x >> 8;
    binned[gbase[b] + (k - lbase[b])] = p;
  }
}

// Pass C: per-bucket CSR build keyed by (dstLocal, srcPhase) -> offs8 + adj
__global__ __launch_bounds__(256) void k_build(const int* __restrict__ bbase,
                                               const uint2* __restrict__ binned,
                                               int* __restrict__ offs8,
                                               int* __restrict__ adj,
                                               int N, int twoE) {
  __shared__ int hist[2048];
  __shared__ int sc[256];
  __shared__ int lcur[2048];
  __shared__ int adjS[BCAP];
  int b = blockIdx.x, t = threadIdx.x;
  int lo = bbase[b], hi = bbase[b + 1];
  int cntb = hi - lo;
  for (int i = t; i < 2048; i += 256) hist[i] = 0;
  __syncthreads();
  for (int k = t; k < cntb; k += 256) {
    uint2 p = binned[lo + k];
    atomicAdd(&hist[((p.x & 255) << 3) | (p.y / NPH)], 1);
  }
  __syncthreads();
  int loc[8];
  int run = 0;
#pragma unroll
  for (int j = 0; j < 8; ++j) {
    loc[j] = run;
    run += hist[(t << 3) | j];
  }
  sc[t] = run;
  __syncthreads();
  for (int off = 1; off < 256; off <<= 1) {
    int u = (t >= off) ? sc[t - off] : 0;
    __syncthreads();
    sc[t] += u;
    __syncthreads();
  }
  int excl0 = sc[t] - run;
  int node = (b << 8) + t;
#pragma unroll
  for (int j = 0; j < 8; ++j) {
    int e = excl0 + loc[j];
    lcur[(t << 3) | j] = e;
    if (node < N) offs8[(size_t)node * 8 + j] = lo + e;
  }
  if (b == NB - 1 && t == 0) offs8[(size_t)N * 8] = twoE;
  __syncthreads();
  for (int k = t; k < cntb; k += 256) {
    uint2 p = binned[lo + k];
    int pos = atomicAdd(&lcur[((p.x & 255) << 3) | (p.y / NPH)], 1);
    adjS[pos] = (int)p.y;
  }
  __syncthreads();
  for (int k = t; k < cntb; k += 256) adj[lo + k] = adjS[k];
}

// Phase-sliced persistent gather-max, round-robin across the wave's 7 nodes:
// each inner trip issues up to 7 independent adj loads + 7 independent h16
// gathers (predicated, wave-uniform conditions) -> ~7 gathers in flight.
__global__ __launch_bounds__(256) void k_nmax(
    const unsigned* __restrict__ h16, const int* __restrict__ offs8,
    const int* __restrict__ adj, unsigned* __restrict__ aggr16) {
  int w = (blockIdx.x << 2) + (threadIdx.x >> 6);  // 0..8191
  int lane = threadIdx.x & 63;
  float ml[7], mh[7];
#pragma unroll
  for (int k = 0; k < 7; ++k) {
    ml[k] = -INFINITY;
    mh[k] = -INFINITY;
  }
  for (int p = 0; p < 8; ++p) {
    int s[7], e[7];
#pragma unroll
    for (int k = 0; k < 7; ++k) {
      int i = w + (k << 13);
      int ic = min(i, NODES - 1);
      s[k] = offs8[(size_t)ic * 8 + p];
      e[k] = (i < NODES) ? offs8[(size_t)ic * 8 + p + 1] : s[k];
    }
    for (;;) {
      int act[7], j[7];
      int any = 0;
#pragma unroll
      for (int k = 0; k < 7; ++k) {
        act[k] = (s[k] < e[k]) ? 1 : 0;
        int idx = act[k] ? s[k] : 0;
        j[k] = adj[idx];
        s[k] += act[k];
        any |= act[k];
      }
      if (!any) break;
      unsigned u[7];
#pragma unroll
      for (int k = 0; k < 7; ++k) u[k] = h16[(size_t)j[k] * 64 + lane];
#pragma unroll
      for (int k = 0; k < 7; ++k) {
        float vlo = act[k] ? __uint_as_float(u[k] << 16) : -INFINITY;
        float vhi = act[k] ? __uint_as_float(u[k] & 0xFFFF0000u) : -INFINITY;
        ml[k] = fmaxf(ml[k], vlo);
        mh[k] = fmaxf(mh[k], vhi);
      }
    }
  }
#pragma unroll
  for (int k = 0; k < 7; ++k) {
    int i = w + (k << 13);
    if (i < NODES) {
      int d0 = offs8[(size_t)i * 8];
      int d1 = offs8[(size_t)i * 8 + 8];
      unsigned us = h16[(size_t)i * 64 + lane];
      float hx = __uint_as_float(us << 16);
      float hy = __uint_as_float(us & 0xFFFF0000u);
      float rx = (d1 > d0) ? (ml[k] - hx) : 0.f;
      float ry = (d1 > d0) ? (mh[k] - hy) : 0.f;
      aggr16[(size_t)i * 64 + lane] = bf16rne(rx) | (bf16rne(ry) << 16);
    }
  }
}

// out16 = bf16(relu([A1|A2] @ W + bias)) via bf16 MFMA, fp32 accumulate.
// Block: 64 rows x 128 cols, 4 waves, K=256 in 8 steps.
// If out16 == nullptr: fused global-max-pool epilogue (sorted batch) instead.
__global__ __launch_bounds__(256) void k_gemm_mfma(
    const uint4* __restrict__ A1, const uint4* __restrict__ A2,
    const uint4* __restrict__ Wb, const float* __restrict__ bias,
    unsigned* __restrict__ out16, const int* __restrict__ batch,
    float* __restrict__ g, int N) {
  __shared__ uint4 Bs[4096];  // 64 KB; reused as Ct[64][132] ushort after MFMAs
  int t = threadIdx.x;
  int m0 = blockIdx.x * 64;
  for (int i = t; i < 4096; i += 256) Bs[i] = Wb[i];
  int wave = t >> 6, lane = t & 63;
  int kg = lane >> 4;
  int arow = m0 + wave * 16 + (lane & 15);
  int arc = min(arow, N - 1);
  const uint4* R1 = A1 + (size_t)arc * 16;
  const uint4* R2 = A2 + (size_t)arc * 16;
  f32x4 acc[8];
#pragma unroll
  for (int nf = 0; nf < 8; ++nf) acc[nf] = (f32x4){0.f, 0.f, 0.f, 0.f};
  __syncthreads();
#pragma unroll
  for (int ks = 0; ks < 8; ++ks) {
    UV a;
    a.u = (ks < 4) ? R1[ks * 4 + kg] : R2[(ks - 4) * 4 + kg];
#pragma unroll
    for (int nf = 0; nf < 8; ++nf) {
      UV b;
      b.u = Bs[(ks * 8 + nf) * 64 + lane];
      acc[nf] = __builtin_amdgcn_mfma_f32_16x16x32_bf16(a.s, b.s, acc[nf], 0, 0, 0);
    }
  }
  __syncthreads();
  unsigned short* Ct = (unsigned short*)Bs;  // [64][132]
#pragma unroll
  for (int nf = 0; nf < 8; ++nf) {
    float bc = bias[nf * 16 + (lane & 15)];
#pragma unroll
    for (int r = 0; r < 4; ++r) {
      int row = wave * 16 + kg * 4 + r;
      float v = fmaxf(acc[nf][r] + bc, 0.f);
      Ct[row * 132 + nf * 16 + (lane & 15)] = (unsigned short)bf16rne(v);
    }
  }
  __syncthreads();
  if (out16) {
    const unsigned* CtU = (const unsigned*)Bs;
    for (int i = t; i < 4096; i += 256) {
      int row = i >> 6, cp = i & 63;
      int gr = m0 + row;
      if (gr < N) out16[(size_t)gr * 64 + cp] = CtU[row * 66 + cp];
    }
  } else if (t < 128) {
    // fused max-pool over this block's 64 sorted-batch rows
    int f = t;
    int cur = -1;
    float m = 0.f;
    for (int r = 0; r < 64; ++r) {
      int gr = m0 + r;
      if (gr >= N) break;
      int bb = batch[gr];
      if (bb != cur) {
        if (cur >= 0) atomicMax((int*)&g[cur * FEAT + f], __float_as_int(m));
        cur = bb;
        m = 0.f;
      }
      unsigned u = (unsigned)Ct[r * 132 + f];
      m = fmaxf(m, __uint_as_float(u << 16));
    }
    if (cur >= 0) atomicMax((int*)&g[cur * FEAT + f], __float_as_int(m));
  }
}

__global__ __launch_bounds__(64) void k_mlp(
    const float* __restrict__ g, const float* __restrict__ Wf1,
    const float* __restrict__ bf1, const float* __restrict__ Wf2,
    const float* __restrict__ bf2, float* __restrict__ out) {
  __shared__ float gr[128];
  __shared__ float h1[64];
  int gi = blockIdx.x, t = threadIdx.x;
  gr[t] = g[gi * FEAT + t];
  gr[t + 64] = g[gi * FEAT + 64 + t];
  __syncthreads();
  float acc = bf1[t];
#pragma unroll 4
  for (int k = 0; k < 128; ++k) acc += gr[k] * Wf1[k * 64 + t];
  h1[t] = fmaxf(acc, 0.f);
  __syncthreads();
  float logit = -INFINITY;
  if (t < 40) {
    float a = bf2[t];
#pragma unroll 4
    for (int k = 0; k < 64; ++k) a += h1[k] * Wf2[k * 40 + t];
    logit = a;
  }
  float m = logit;
#pragma unroll
  for (int off = 32; off; off >>= 1) m = fmaxf(m, __shfl_xor(m, off));
  float e = (t < 40) ? expf(logit - m) : 0.f;
  float s = e;
#pragma unroll
  for (int off = 32; off; off >>= 1) s += __shfl_xor(s, off);
  if (t < 40) out[gi * 40 + t] = logit - m - logf(s);
}

extern "C" void kernel_launch(void* const* d_in, const int* in_sizes, int n_in,
                              void* d_out, int out_size, void* d_ws, size_t ws_size,
                              hipStream_t stream) {
  const float* x = (const float*)d_in[0];
  const int* ei = (const int*)d_in[1];
  const int* batch = (const int*)d_in[2];
  const float* W1 = (const float*)d_in[3];
  const float* b1 = (const float*)d_in[4];
  const float* W2 = (const float*)d_in[5];
  const float* b2 = (const float*)d_in[6];
  const float* W3 = (const float*)d_in[7];
  const float* b3 = (const float*)d_in[8];
  const float* Wf1 = (const float*)d_in[9];
  const float* bf1 = (const float*)d_in[10];
  const float* Wf2 = (const float*)d_in[11];
  const float* bf2 = (const float*)d_in[12];
  float* out = (float*)d_out;

  const int N = NODES;
  const int E = in_sizes[1] / 2;  // 800000 original edges
  const int* src = ei;
  const int* dst = ei + E;

  char* ws = (char*)d_ws;
  size_t off = 0;
  auto carve = [&](size_t bytes) {
    void* p = ws + off;
    off += (bytes + 255) & ~(size_t)255;
    return p;
  };
  unsigned* hA16 = (unsigned*)carve((size_t)N * 64 * 4);
  unsigned* hB16 = (unsigned*)carve((size_t)N * 64 * 4);
  unsigned* aggr16 = (unsigned*)carve((size_t)N * 64 * 4);  // binned aliases this
  uint4* Wb1 = (uint4*)carve(65536);
  uint4* Wb2 = (uint4*)carve(65536);
  uint4* Wb3 = (uint4*)carve(65536);
  int* zreg = (int*)carve((size_t)8704 * 4);  // bcount(256) | bcur(256) | g(8192)
  int* bcount = zreg;
  int* bcur = zreg + 256;
  float* g = (float*)(zreg + 512);
  int* bbase = (int*)carve((size_t)(NB + 1) * 4);
  int* offs8 = (int*)carve(((size_t)N * 8 + 1) * 4);
  int* adj = (int*)carve((size_t)2 * E * 4);
  uint2* binned = (uint2*)aggr16;  // 12.8 MB, dead until first k_nmax

  const int nEB = (E + 4095) / 4096;  // 196 edge-chunk blocks
  const int nMB = (N + 63) / 64;      // 782 GEMM blocks

  // ---- prep (cast + wpack + zero) and binned CSR build ----
  k_prep<<<12582, 256, 0, stream>>>(x, W1, W2, W3, hA16, Wb1, Wb2, Wb3, zreg);
  k_bcount<<<nEB, 256, 0, stream>>>(src, dst, E, bcount);
  k_bscan<<<1, 256, 0, stream>>>(bcount, bbase, 2 * E);
  k_bin<<<nEB, 256, 0, stream>>>(src, dst, E, bbase, bcur, binned);
  k_build<<<NB, 256, 0, stream>>>(bbase, binned, offs8, adj, N, 2 * E);

  // ---- 3x MRConv (phase-sliced bf16 gather-max, bf16 MFMA concat-GEMM) ----
  k_nmax<<<2048, 256, 0, stream>>>(hA16, offs8, adj, aggr16);
  k_gemm_mfma<<<nMB, 256, 0, stream>>>((const uint4*)hA16, (const uint4*)aggr16,
                                       Wb1, b1, hB16, batch, g, N);
  k_nmax<<<2048, 256, 0, stream>>>(hB16, offs8, adj, aggr16);
  k_gemm_mfma<<<nMB, 256, 0, stream>>>((const uint4*)hB16, (const uint4*)aggr16,
                                       Wb2, b2, hA16, batch, g, N);
  k_nmax<<<2048, 256, 0, stream>>>(hA16, offs8, adj, aggr16);
  k_gemm_mfma<<<nMB, 256, 0, stream>>>((const uint4*)hA16, (const uint4*)aggr16,
                                       Wb3, b3, (unsigned*)nullptr, batch, g, N);

  // ---- MLP head + log_softmax (pool fused into last GEMM) ----
  k_mlp<<<64, 64, 0, stream>>>(g, Wf1, bf1, Wf2, bf2, out);
}

// Round 13
// 367.684 us; speedup vs baseline: 1.8876x; 1.8876x over previous
//
#include <hip/hip_runtime.h>
#include <hip/hip_bf16.h>
#include <math.h>

#define NODES 50000
#define FEAT 128
#define NB 196          // ceil(50000/256) buckets of 256 nodes
#define BCAP 12288      // per-bucket adj capacity (mean 8192, sd ~90)
#define NPH 6250        // src-phase slice width (kept: gives sorted-by-src runs)

typedef __attribute__((ext_vector_type(4))) float f32x4;
typedef __attribute__((ext_vector_type(8))) short short8;
union UV { uint4 u; short8 s; };

__device__ __forceinline__ unsigned bf16rne(float x) {
  unsigned u = __float_as_uint(x);
  return (u + 0x7FFFu + ((u >> 16) & 1u)) >> 16;  // RNE, result in low 16
}

// fused: cast x -> packed bf16 | pack 3 weight matrices | zero bcount/bcur/g
__global__ __launch_bounds__(256) void k_prep(
    const float* __restrict__ x, const float* __restrict__ W1,
    const float* __restrict__ W2, const float* __restrict__ W3,
    unsigned* __restrict__ h16, uint4* __restrict__ Wb1,
    uint4* __restrict__ Wb2, uint4* __restrict__ Wb3, int* __restrict__ zreg) {
  int b = blockIdx.x, t = threadIdx.x;
  if (b < 12500) {                       // cast: 12500*256 == NODES*64 exactly
    int i = b * 256 + t;
    float2 v = ((const float2*)x)[i];
    h16[i] = bf16rne(v.x) | (bf16rne(v.y) << 16);
  } else if (b < 12548) {                // wpack: 3 x 16 blocks
    int q = b - 12500;
    const float* __restrict__ W = (q < 16) ? W1 : (q < 32) ? W2 : W3;
    uint4* __restrict__ Wb = (q < 16) ? Wb1 : (q < 32) ? Wb2 : Wb3;
    int tid = (q & 15) * 256 + t;        // 0..4095
    int lane = tid & 63, nf = (tid >> 6) & 7, ks = tid >> 9;
    int kb = ks * 32 + (lane >> 4) * 8;
    int col = nf * 16 + (lane & 15);
    uint4 r;
    r.x = bf16rne(W[(kb + 0) * FEAT + col]) | (bf16rne(W[(kb + 1) * FEAT + col]) << 16);
    r.y = bf16rne(W[(kb + 2) * FEAT + col]) | (bf16rne(W[(kb + 3) * FEAT + col]) << 16);
    r.z = bf16rne(W[(kb + 4) * FEAT + col]) | (bf16rne(W[(kb + 5) * FEAT + col]) << 16);
    r.w = bf16rne(W[(kb + 6) * FEAT + col]) | (bf16rne(W[(kb + 7) * FEAT + col]) << 16);
    Wb[tid] = r;
  } else {                               // zero bcount|bcur|g : 8704 ints
    int i = (b - 12548) * 256 + t;
    if (i < 8704) zreg[i] = 0;
  }
}

// Pass A: coarse bucket histogram (bucket = node >> 8), LDS-aggregated
__global__ __launch_bounds__(256) void k_bcount(const int* __restrict__ src,
                                                const int* __restrict__ dst,
                                                int E, int* __restrict__ bcount) {
  __shared__ int cnt[NB];
  int t = threadIdx.x;
  for (int i = t; i < NB; i += 256) cnt[i] = 0;
  __syncthreads();
  int base = blockIdx.x * 4096;
  int nE = min(4096, E - base);
  for (int k = t; k < nE; k += 256) {
    int s = src[base + k], d = dst[base + k];
    atomicAdd(&cnt[d >> 8], 1);
    atomicAdd(&cnt[s >> 8], 1);
  }
  __syncthreads();
  for (int i = t; i < NB; i += 256)
    if (cnt[i]) atomicAdd(&bcount[i], cnt[i]);
}

// exclusive scan of NB bucket counts -> bbase[NB+1]
__global__ __launch_bounds__(256) void k_bscan(const int* __restrict__ bcount,
                                               int* __restrict__ bbase, int twoE) {
  __shared__ int sc[256];
  int t = threadIdx.x;
  int v = (t < NB) ? bcount[t] : 0;
  sc[t] = v;
  __syncthreads();
  for (int off = 1; off < 256; off <<= 1) {
    int u = (t >= off) ? sc[t - off] : 0;
    __syncthreads();
    sc[t] += u;
    __syncthreads();
  }
  if (t < NB) bbase[t] = sc[t] - v;
  if (t == 0) bbase[NB] = twoE;
}

// Pass B: bucket-sort (d,s) pairs via LDS staging, flush in contiguous runs
__global__ __launch_bounds__(256) void k_bin(const int* __restrict__ src,
                                             const int* __restrict__ dst, int E,
                                             const int* __restrict__ bbase,
                                             int* __restrict__ bcur,
                                             uint2* __restrict__ binned) {
  __shared__ uint2 stage[8192];
  __shared__ int cnt[NB];
  __shared__ int lbase[NB];
  __shared__ int gbase[NB];
  __shared__ int lcur[NB];
  __shared__ int sc[256];
  int t = threadIdx.x;
  for (int i = t; i < NB; i += 256) cnt[i] = 0;
  __syncthreads();
  int base = blockIdx.x * 4096;
  int nE = min(4096, E - base);
  for (int k = t; k < nE; k += 256) {
    int s = src[base + k], d = dst[base + k];
    atomicAdd(&cnt[d >> 8], 1);
    atomicAdd(&cnt[s >> 8], 1);
  }
  __syncthreads();
  int v = (t < NB) ? cnt[t] : 0;
  sc[t] = v;
  __syncthreads();
  for (int off = 1; off < 256; off <<= 1) {
    int u = (t >= off) ? sc[t - off] : 0;
    __syncthreads();
    sc[t] += u;
    __syncthreads();
  }
  if (t < NB) {
    lbase[t] = sc[t] - v;
    lcur[t] = sc[t] - v;
  }
  __syncthreads();
  int total = sc[255];
  for (int k = t; k < nE; k += 256) {
    int s = src[base + k], d = dst[base + k];
    int p1 = atomicAdd(&lcur[d >> 8], 1);
    stage[p1] = make_uint2((unsigned)d, (unsigned)s);
    int p2 = atomicAdd(&lcur[s >> 8], 1);
    stage[p2] = make_uint2((unsigned)s, (unsigned)d);
  }
  __syncthreads();
  if (t < NB && cnt[t] > 0) gbase[t] = bbase[t] + atomicAdd(&bcur[t], cnt[t]);
  __syncthreads();
  for (int k = t; k < total; k += 256) {
    uint2 p = stage[k];
    int b = p.x >> 8;
    binned[gbase[b] + (k - lbase[b])] = p;
  }
}

// Pass C: per-bucket CSR build keyed by (dstLocal, srcPhase) -> offs8 + adj.
// Node i's full neighbor run is [offs8[i*8], offs8[(i+1)*8]) (phases adjacent).
__global__ __launch_bounds__(256) void k_build(const int* __restrict__ bbase,
                                               const uint2* __restrict__ binned,
                                               int* __restrict__ offs8,
                                               int* __restrict__ adj,
                                               int N, int twoE) {
  __shared__ int hist[2048];
  __shared__ int sc[256];
  __shared__ int lcur[2048];
  __shared__ int adjS[BCAP];
  int b = blockIdx.x, t = threadIdx.x;
  int lo = bbase[b], hi = bbase[b + 1];
  int cntb = hi - lo;
  for (int i = t; i < 2048; i += 256) hist[i] = 0;
  __syncthreads();
  for (int k = t; k < cntb; k += 256) {
    uint2 p = binned[lo + k];
    atomicAdd(&hist[((p.x & 255) << 3) | (p.y / NPH)], 1);
  }
  __syncthreads();
  int loc[8];
  int run = 0;
#pragma unroll
  for (int j = 0; j < 8; ++j) {
    loc[j] = run;
    run += hist[(t << 3) | j];
  }
  sc[t] = run;
  __syncthreads();
  for (int off = 1; off < 256; off <<= 1) {
    int u = (t >= off) ? sc[t - off] : 0;
    __syncthreads();
    sc[t] += u;
    __syncthreads();
  }
  int excl0 = sc[t] - run;
  int node = (b << 8) + t;
#pragma unroll
  for (int j = 0; j < 8; ++j) {
    int e = excl0 + loc[j];
    lcur[(t << 3) | j] = e;
    if (node < N) offs8[(size_t)node * 8 + j] = lo + e;
  }
  if (b == NB - 1 && t == 0) offs8[(size_t)N * 8] = twoE;
  __syncthreads();
  for (int k = t; k < cntb; k += 256) {
    uint2 p = binned[lo + k];
    int pos = atomicAdd(&lcur[((p.x & 255) << 3) | (p.y / NPH)], 1);
    adjS[pos] = (int)p.y;
  }
  __syncthreads();
  for (int k = t; k < cntb; k += 256) adj[lo + k] = adjS[k];
}

// aggr16[i] = bf16( (deg>0) ? max_j bf16(h[j]) - bf16(h[i]) : 0 )
// one wave per node, full neighbor run, 8-deep independent load chains
__global__ __launch_bounds__(256) void k_nmax(
    const unsigned* __restrict__ h16, const int* __restrict__ offs8,
    const int* __restrict__ adj, unsigned* __restrict__ aggr16) {
  int i = blockIdx.x * 4 + (threadIdx.x >> 6);
  int lane = threadIdx.x & 63;
  int o0 = offs8[(size_t)i * 8];
  int o1 = offs8[(size_t)(i + 1) * 8];
  float mlo0 = -INFINITY, mhi0 = -INFINITY;
  float mlo1 = -INFINITY, mhi1 = -INFINITY;
  float mlo2 = -INFINITY, mhi2 = -INFINITY;
  float mlo3 = -INFINITY, mhi3 = -INFINITY;
  int e = o0;
  for (; e + 8 <= o1; e += 8) {
    int j0 = adj[e], j1 = adj[e + 1], j2 = adj[e + 2], j3 = adj[e + 3];
    int j4 = adj[e + 4], j5 = adj[e + 5], j6 = adj[e + 6], j7 = adj[e + 7];
    unsigned u0 = h16[(size_t)j0 * 64 + lane];
    unsigned u1 = h16[(size_t)j1 * 64 + lane];
    unsigned u2 = h16[(size_t)j2 * 64 + lane];
    unsigned u3 = h16[(size_t)j3 * 64 + lane];
    unsigned u4 = h16[(size_t)j4 * 64 + lane];
    unsigned u5 = h16[(size_t)j5 * 64 + lane];
    unsigned u6 = h16[(size_t)j6 * 64 + lane];
    unsigned u7 = h16[(size_t)j7 * 64 + lane];
    mlo0 = fmaxf(mlo0, __uint_as_float(u0 << 16));
    mhi0 = fmaxf(mhi0, __uint_as_float(u0 & 0xFFFF0000u));
    mlo1 = fmaxf(mlo1, __uint_as_float(u1 << 16));
    mhi1 = fmaxf(mhi1, __uint_as_float(u1 & 0xFFFF0000u));
    mlo2 = fmaxf(mlo2, __uint_as_float(u2 << 16));
    mhi2 = fmaxf(mhi2, __uint_as_float(u2 & 0xFFFF0000u));
    mlo3 = fmaxf(mlo3, __uint_as_float(u3 << 16));
    mhi3 = fmaxf(mhi3, __uint_as_float(u3 & 0xFFFF0000u));
    mlo0 = fmaxf(mlo0, __uint_as_float(u4 << 16));
    mhi0 = fmaxf(mhi0, __uint_as_float(u4 & 0xFFFF0000u));
    mlo1 = fmaxf(mlo1, __uint_as_float(u5 << 16));
    mhi1 = fmaxf(mhi1, __uint_as_float(u5 & 0xFFFF0000u));
    mlo2 = fmaxf(mlo2, __uint_as_float(u6 << 16));
    mhi2 = fmaxf(mhi2, __uint_as_float(u6 & 0xFFFF0000u));
    mlo3 = fmaxf(mlo3, __uint_as_float(u7 << 16));
    mhi3 = fmaxf(mhi3, __uint_as_float(u7 & 0xFFFF0000u));
  }
  for (; e + 2 <= o1; e += 2) {
    int j0 = adj[e], j1 = adj[e + 1];
    unsigned u0 = h16[(size_t)j0 * 64 + lane];
    unsigned u1 = h16[(size_t)j1 * 64 + lane];
    mlo0 = fmaxf(mlo0, __uint_as_float(u0 << 16));
    mhi0 = fmaxf(mhi0, __uint_as_float(u0 & 0xFFFF0000u));
    mlo1 = fmaxf(mlo1, __uint_as_float(u1 << 16));
    mhi1 = fmaxf(mhi1, __uint_as_float(u1 & 0xFFFF0000u));
  }
  if (e < o1) {
    unsigned u0 = h16[(size_t)adj[e] * 64 + lane];
    mlo0 = fmaxf(mlo0, __uint_as_float(u0 << 16));
    mhi0 = fmaxf(mhi0, __uint_as_float(u0 & 0xFFFF0000u));
  }
  float mlo = fmaxf(fmaxf(mlo0, mlo1), fmaxf(mlo2, mlo3));
  float mhi = fmaxf(fmaxf(mhi0, mhi1), fmaxf(mhi2, mhi3));
  unsigned us = h16[(size_t)i * 64 + lane];
  float hx = __uint_as_float(us << 16);
  float hy = __uint_as_float(us & 0xFFFF0000u);
  float rx = (o1 > o0) ? (mlo - hx) : 0.f;
  float ry = (o1 > o0) ? (mhi - hy) : 0.f;
  aggr16[(size_t)i * 64 + lane] = bf16rne(rx) | (bf16rne(ry) << 16);
}

// out16 = bf16(relu([A1|A2] @ W + bias)) via bf16 MFMA, fp32 accumulate.
// Block: 64 rows x 128 cols, 4 waves, K=256 in 8 steps.
// If out16 == nullptr: fused global-max-pool epilogue (sorted batch) instead.
__global__ __launch_bounds__(256) void k_gemm_mfma(
    const uint4* __restrict__ A1, const uint4* __restrict__ A2,
    const uint4* __restrict__ Wb, const float* __restrict__ bias,
    unsigned* __restrict__ out16, const int* __restrict__ batch,
    float* __restrict__ g, int N) {
  __shared__ uint4 Bs[4096];  // 64 KB; reused as Ct[64][132] ushort after MFMAs
  int t = threadIdx.x;
  int m0 = blockIdx.x * 64;
  for (int i = t; i < 4096; i += 256) Bs[i] = Wb[i];
  int wave = t >> 6, lane = t & 63;
  int kg = lane >> 4;
  int arow = m0 + wave * 16 + (lane & 15);
  int arc = min(arow, N - 1);
  const uint4* R1 = A1 + (size_t)arc * 16;
  const uint4* R2 = A2 + (size_t)arc * 16;
  f32x4 acc[8];
#pragma unroll
  for (int nf = 0; nf < 8; ++nf) acc[nf] = (f32x4){0.f, 0.f, 0.f, 0.f};
  __syncthreads();
#pragma unroll
  for (int ks = 0; ks < 8; ++ks) {
    UV a;
    a.u = (ks < 4) ? R1[ks * 4 + kg] : R2[(ks - 4) * 4 + kg];
#pragma unroll
    for (int nf = 0; nf < 8; ++nf) {
      UV b;
      b.u = Bs[(ks * 8 + nf) * 64 + lane];
      acc[nf] = __builtin_amdgcn_mfma_f32_16x16x32_bf16(a.s, b.s, acc[nf], 0, 0, 0);
    }
  }
  __syncthreads();
  unsigned short* Ct = (unsigned short*)Bs;  // [64][132]
#pragma unroll
  for (int nf = 0; nf < 8; ++nf) {
    float bc = bias[nf * 16 + (lane & 15)];
#pragma unroll
    for (int r = 0; r < 4; ++r) {
      int row = wave * 16 + kg * 4 + r;
      float v = fmaxf(acc[nf][r] + bc, 0.f);
      Ct[row * 132 + nf * 16 + (lane & 15)] = (unsigned short)bf16rne(v);
    }
  }
  __syncthreads();
  if (out16) {
    const unsigned* CtU = (const unsigned*)Bs;
    for (int i = t; i < 4096; i += 256) {
      int row = i >> 6, cp = i & 63;
      int gr = m0 + row;
      if (gr < N) out16[(size_t)gr * 64 + cp] = CtU[row * 66 + cp];
    }
  } else if (t < 128) {
    // fused max-pool over this block's 64 sorted-batch rows
    int f = t;
    int cur = -1;
    float m = 0.f;
    for (int r = 0; r < 64; ++r) {
      int gr = m0 + r;
      if (gr >= N) break;
      int bb = batch[gr];
      if (bb != cur) {
        if (cur >= 0) atomicMax((int*)&g[cur * FEAT + f], __float_as_int(m));
        cur = bb;
        m = 0.f;
      }
      unsigned u = (unsigned)Ct[r * 132 + f];
      m = fmaxf(m, __uint_as_float(u << 16));
    }
    if (cur >= 0) atomicMax((int*)&g[cur * FEAT + f], __float_as_int(m));
  }
}

__global__ __launch_bounds__(64) void k_mlp(
    const float* __restrict__ g, const float* __restrict__ Wf1,
    const float* __restrict__ bf1, const float* __restrict__ Wf2,
    const float* __restrict__ bf2, float* __restrict__ out) {
  __shared__ float gr[128];
  __shared__ float h1[64];
  int gi = blockIdx.x, t = threadIdx.x;
  gr[t] = g[gi * FEAT + t];
  gr[t + 64] = g[gi * FEAT + 64 + t];
  __syncthreads();
  float acc = bf1[t];
#pragma unroll 4
  for (int k = 0; k < 128; ++k) acc += gr[k] * Wf1[k * 64 + t];
  h1[t] = fmaxf(acc, 0.f);
  __syncthreads();
  float logit = -INFINITY;
  if (t < 40) {
    float a = bf2[t];
#pragma unroll 4
    for (int k = 0; k < 64; ++k) a += h1[k] * Wf2[k * 40 + t];
    logit = a;
  }
  float m = logit;
#pragma unroll
  for (int off = 32; off; off >>= 1) m = fmaxf(m, __shfl_xor(m, off));
  float e = (t < 40) ? expf(logit - m) : 0.f;
  float s = e;
#pragma unroll
  for (int off = 32; off; off >>= 1) s += __shfl_xor(s, off);
  if (t < 40) out[gi * 40 + t] = logit - m - logf(s);
}

extern "C" void kernel_launch(void* const* d_in, const int* in_sizes, int n_in,
                              void* d_out, int out_size, void* d_ws, size_t ws_size,
                              hipStream_t stream) {
  const float* x = (const float*)d_in[0];
  const int* ei = (const int*)d_in[1];
  const int* batch = (const int*)d_in[2];
  const float* W1 = (const float*)d_in[3];
  const float* b1 = (const float*)d_in[4];
  const float* W2 = (const float*)d_in[5];
  const float* b2 = (const float*)d_in[6];
  const float* W3 = (const float*)d_in[7];
  const float* b3 = (const float*)d_in[8];
  const float* Wf1 = (const float*)d_in[9];
  const float* bf1 = (const float*)d_in[10];
  const float* Wf2 = (const float*)d_in[11];
  const float* bf2 = (const float*)d_in[12];
  float* out = (float*)d_out;

  const int N = NODES;
  const int E = in_sizes[1] / 2;  // 800000 original edges
  const int* src = ei;
  const int* dst = ei + E;

  char* ws = (char*)d_ws;
  size_t off = 0;
  auto carve = [&](size_t bytes) {
    void* p = ws + off;
    off += (bytes + 255) & ~(size_t)255;
    return p;
  };
  unsigned* hA16 = (unsigned*)carve((size_t)N * 64 * 4);
  unsigned* hB16 = (unsigned*)carve((size_t)N * 64 * 4);
  unsigned* aggr16 = (unsigned*)carve((size_t)N * 64 * 4);  // binned aliases this
  uint4* Wb1 = (uint4*)carve(65536);
  uint4* Wb2 = (uint4*)carve(65536);
  uint4* Wb3 = (uint4*)carve(65536);
  int* zreg = (int*)carve((size_t)8704 * 4);  // bcount(256) | bcur(256) | g(8192)
  int* bcount = zreg;
  int* bcur = zreg + 256;
  float* g = (float*)(zreg + 512);
  int* bbase = (int*)carve((size_t)(NB + 1) * 4);
  int* offs8 = (int*)carve(((size_t)N * 8 + 1) * 4);
  int* adj = (int*)carve((size_t)2 * E * 4);
  uint2* binned = (uint2*)aggr16;  // 12.8 MB, dead until first k_nmax

  const int nEB = (E + 4095) / 4096;  // 196 edge-chunk blocks
  const int nMB = (N + 63) / 64;      // 782 GEMM blocks

  // ---- prep (cast + wpack + zero) and binned CSR build ----
  k_prep<<<12582, 256, 0, stream>>>(x, W1, W2, W3, hA16, Wb1, Wb2, Wb3, zreg);
  k_bcount<<<nEB, 256, 0, stream>>>(src, dst, E, bcount);
  k_bscan<<<1, 256, 0, stream>>>(bcount, bbase, 2 * E);
  k_bin<<<nEB, 256, 0, stream>>>(src, dst, E, bbase, bcur, binned);
  k_build<<<NB, 256, 0, stream>>>(bbase, binned, offs8, adj, N, 2 * E);

  // ---- 3x MRConv (bf16 gather-max, bf16 MFMA concat-GEMM) ----
  k_nmax<<<N / 4, 256, 0, stream>>>(hA16, offs8, adj, aggr16);
  k_gemm_mfma<<<nMB, 256, 0, stream>>>((const uint4*)hA16, (const uint4*)aggr16,
                                       Wb1, b1, hB16, batch, g, N);
  k_nmax<<<N / 4, 256, 0, stream>>>(hB16, offs8, adj, aggr16);
  k_gemm_mfma<<<nMB, 256, 0, stream>>>((const uint4*)hB16, (const uint4*)aggr16,
                                       Wb2, b2, hA16, batch, g, N);
  k_nmax<<<N / 4, 256, 0, stream>>>(hA16, offs8, adj, aggr16);
  k_gemm_mfma<<<nMB, 256, 0, stream>>>((const uint4*)hA16, (const uint4*)aggr16,
                                       Wb3, b3, (unsigned*)nullptr, batch, g, N);

  // ---- MLP head + log_softmax (pool fused into last GEMM) ----
  k_mlp<<<64, 64, 0, stream>>>(g, Wf1, bf1, Wf2, bf2, out);
}

// Round 14
// 351.789 us; speedup vs baseline: 1.9729x; 1.0452x over previous
//
#include <hip/hip_runtime.h>
#include <hip/hip_bf16.h>
#include <math.h>

#define NODES 50000
#define FEAT 128
#define NB 196          // ceil(50000/256) buckets of 256 nodes
#define BCAP 12288      // per-bucket adj capacity (mean 8192, sd ~90)
#define NPH 6250        // src-phase slice width (gives sorted-by-src runs)

typedef __attribute__((ext_vector_type(4))) float f32x4;
typedef __attribute__((ext_vector_type(8))) short short8;
union UV { uint4 u; short8 s; };

__device__ __forceinline__ unsigned bf16rne(float x) {
  unsigned u = __float_as_uint(x);
  return (u + 0x7FFFu + ((u >> 16) & 1u)) >> 16;  // RNE, result in low 16
}

// fused: cast x -> packed bf16 | pack 3 weight matrices | zero bcount/bcur/g
__global__ __launch_bounds__(256) void k_prep(
    const float* __restrict__ x, const float* __restrict__ W1,
    const float* __restrict__ W2, const float* __restrict__ W3,
    unsigned* __restrict__ h16, uint4* __restrict__ Wb1,
    uint4* __restrict__ Wb2, uint4* __restrict__ Wb3, int* __restrict__ zreg) {
  int b = blockIdx.x, t = threadIdx.x;
  if (b < 12500) {                       // cast: 12500*256 == NODES*64 exactly
    int i = b * 256 + t;
    float2 v = ((const float2*)x)[i];
    h16[i] = bf16rne(v.x) | (bf16rne(v.y) << 16);
  } else if (b < 12548) {                // wpack: 3 x 16 blocks
    int q = b - 12500;
    const float* __restrict__ W = (q < 16) ? W1 : (q < 32) ? W2 : W3;
    uint4* __restrict__ Wb = (q < 16) ? Wb1 : (q < 32) ? Wb2 : Wb3;
    int tid = (q & 15) * 256 + t;        // 0..4095
    int lane = tid & 63, nf = (tid >> 6) & 7, ks = tid >> 9;
    int kb = ks * 32 + (lane >> 4) * 8;
    int col = nf * 16 + (lane & 15);
    uint4 r;
    r.x = bf16rne(W[(kb + 0) * FEAT + col]) | (bf16rne(W[(kb + 1) * FEAT + col]) << 16);
    r.y = bf16rne(W[(kb + 2) * FEAT + col]) | (bf16rne(W[(kb + 3) * FEAT + col]) << 16);
    r.z = bf16rne(W[(kb + 4) * FEAT + col]) | (bf16rne(W[(kb + 5) * FEAT + col]) << 16);
    r.w = bf16rne(W[(kb + 6) * FEAT + col]) | (bf16rne(W[(kb + 7) * FEAT + col]) << 16);
    Wb[tid] = r;
  } else {                               // zero bcount|bcur|g : 8704 ints
    int i = (b - 12548) * 256 + t;
    if (i < 8704) zreg[i] = 0;
  }
}

// Pass A: coarse bucket histogram (bucket = node >> 8), LDS-aggregated
__global__ __launch_bounds__(256) void k_bcount(const int* __restrict__ src,
                                                const int* __restrict__ dst,
                                                int E, int* __restrict__ bcount) {
  __shared__ int cnt[NB];
  int t = threadIdx.x;
  for (int i = t; i < NB; i += 256) cnt[i] = 0;
  __syncthreads();
  int base = blockIdx.x * 4096;
  int nE = min(4096, E - base);
  for (int k = t; k < nE; k += 256) {
    int s = src[base + k], d = dst[base + k];
    atomicAdd(&cnt[d >> 8], 1);
    atomicAdd(&cnt[s >> 8], 1);
  }
  __syncthreads();
  for (int i = t; i < NB; i += 256)
    if (cnt[i]) atomicAdd(&bcount[i], cnt[i]);
}

// exclusive scan of NB bucket counts -> bbase[NB+1]
__global__ __launch_bounds__(256) void k_bscan(const int* __restrict__ bcount,
                                               int* __restrict__ bbase, int twoE) {
  __shared__ int sc[256];
  int t = threadIdx.x;
  int v = (t < NB) ? bcount[t] : 0;
  sc[t] = v;
  __syncthreads();
  for (int off = 1; off < 256; off <<= 1) {
    int u = (t >= off) ? sc[t - off] : 0;
    __syncthreads();
    sc[t] += u;
    __syncthreads();
  }
  if (t < NB) bbase[t] = sc[t] - v;
  if (t == 0) bbase[NB] = twoE;
}

// Pass B: bucket-sort (d,s) pairs via LDS staging, flush in contiguous runs
__global__ __launch_bounds__(256) void k_bin(const int* __restrict__ src,
                                             const int* __restrict__ dst, int E,
                                             const int* __restrict__ bbase,
                                             int* __restrict__ bcur,
                                             uint2* __restrict__ binned) {
  __shared__ uint2 stage[8192];
  __shared__ int cnt[NB];
  __shared__ int lbase[NB];
  __shared__ int gbase[NB];
  __shared__ int lcur[NB];
  __shared__ int sc[256];
  int t = threadIdx.x;
  for (int i = t; i < NB; i += 256) cnt[i] = 0;
  __syncthreads();
  int base = blockIdx.x * 4096;
  int nE = min(4096, E - base);
  for (int k = t; k < nE; k += 256) {
    int s = src[base + k], d = dst[base + k];
    atomicAdd(&cnt[d >> 8], 1);
    atomicAdd(&cnt[s >> 8], 1);
  }
  __syncthreads();
  int v = (t < NB) ? cnt[t] : 0;
  sc[t] = v;
  __syncthreads();
  for (int off = 1; off < 256; off <<= 1) {
    int u = (t >= off) ? sc[t - off] : 0;
    __syncthreads();
    sc[t] += u;
    __syncthreads();
  }
  if (t < NB) {
    lbase[t] = sc[t] - v;
    lcur[t] = sc[t] - v;
  }
  __syncthreads();
  int total = sc[255];
  for (int k = t; k < nE; k += 256) {
    int s = src[base + k], d = dst[base + k];
    int p1 = atomicAdd(&lcur[d >> 8], 1);
    stage[p1] = make_uint2((unsigned)d, (unsigned)s);
    int p2 = atomicAdd(&lcur[s >> 8], 1);
    stage[p2] = make_uint2((unsigned)s, (unsigned)d);
  }
  __syncthreads();
  if (t < NB && cnt[t] > 0) gbase[t] = bbase[t] + atomicAdd(&bcur[t], cnt[t]);
  __syncthreads();
  for (int k = t; k < total; k += 256) {
    uint2 p = stage[k];
    int b = p.x >> 8;
    binned[gbase[b] + (k - lbase[b])] = p;
  }
}

// Pass C: per-bucket CSR build keyed by (dstLocal, srcPhase) -> offs8 + adj.
// Node i's full neighbor run is [offs8[i*8], offs8[(i+1)*8]) (phases adjacent).
__global__ __launch_bounds__(256) void k_build(const int* __restrict__ bbase,
                                               const uint2* __restrict__ binned,
                                               int* __restrict__ offs8,
                                               int* __restrict__ adj,
                                               int N, int twoE) {
  __shared__ int hist[2048];
  __shared__ int sc[256];
  __shared__ int lcur[2048];
  __shared__ int adjS[BCAP];
  int b = blockIdx.x, t = threadIdx.x;
  int lo = bbase[b], hi = bbase[b + 1];
  int cntb = hi - lo;
  for (int i = t; i < 2048; i += 256) hist[i] = 0;
  __syncthreads();
  for (int k = t; k < cntb; k += 256) {
    uint2 p = binned[lo + k];
    atomicAdd(&hist[((p.x & 255) << 3) | (p.y / NPH)], 1);
  }
  __syncthreads();
  int loc[8];
  int run = 0;
#pragma unroll
  for (int j = 0; j < 8; ++j) {
    loc[j] = run;
    run += hist[(t << 3) | j];
  }
  sc[t] = run;
  __syncthreads();
  for (int off = 1; off < 256; off <<= 1) {
    int u = (t >= off) ? sc[t - off] : 0;
    __syncthreads();
    sc[t] += u;
    __syncthreads();
  }
  int excl0 = sc[t] - run;
  int node = (b << 8) + t;
#pragma unroll
  for (int j = 0; j < 8; ++j) {
    int e = excl0 + loc[j];
    lcur[(t << 3) | j] = e;
    if (node < N) offs8[(size_t)node * 8 + j] = lo + e;
  }
  if (b == NB - 1 && t == 0) offs8[(size_t)N * 8] = twoE;
  __syncthreads();
  for (int k = t; k < cntb; k += 256) {
    uint2 p = binned[lo + k];
    int pos = atomicAdd(&lcur[((p.x & 255) << 3) | (p.y / NPH)], 1);
    adjS[pos] = (int)p.y;
  }
  __syncthreads();
  for (int k = t; k < cntb; k += 256) adj[lo + k] = adjS[k];
}

// aggr16[i] = bf16( (deg>0) ? max_j bf16(h[j]) - bf16(h[i]) : 0 )
// one wave per node, full neighbor run, 16-deep independent load chains
__global__ __launch_bounds__(256) void k_nmax(
    const unsigned* __restrict__ h16, const int* __restrict__ offs8,
    const int* __restrict__ adj, unsigned* __restrict__ aggr16) {
  int i = blockIdx.x * 4 + (threadIdx.x >> 6);
  int lane = threadIdx.x & 63;
  int o0 = offs8[(size_t)i * 8];
  int o1 = offs8[(size_t)(i + 1) * 8];
  float ml[4], mh[4];
#pragma unroll
  for (int q = 0; q < 4; ++q) {
    ml[q] = -INFINITY;
    mh[q] = -INFINITY;
  }
  int e = o0;
  for (; e + 16 <= o1; e += 16) {
    int j[16];
#pragma unroll
    for (int q = 0; q < 16; ++q) j[q] = adj[e + q];
    unsigned u[16];
#pragma unroll
    for (int q = 0; q < 16; ++q) u[q] = h16[(size_t)j[q] * 64 + lane];
#pragma unroll
    for (int q = 0; q < 16; ++q) {
      ml[q & 3] = fmaxf(ml[q & 3], __uint_as_float(u[q] << 16));
      mh[q & 3] = fmaxf(mh[q & 3], __uint_as_float(u[q] & 0xFFFF0000u));
    }
  }
  for (; e + 8 <= o1; e += 8) {
    int j[8];
#pragma unroll
    for (int q = 0; q < 8; ++q) j[q] = adj[e + q];
    unsigned u[8];
#pragma unroll
    for (int q = 0; q < 8; ++q) u[q] = h16[(size_t)j[q] * 64 + lane];
#pragma unroll
    for (int q = 0; q < 8; ++q) {
      ml[q & 3] = fmaxf(ml[q & 3], __uint_as_float(u[q] << 16));
      mh[q & 3] = fmaxf(mh[q & 3], __uint_as_float(u[q] & 0xFFFF0000u));
    }
  }
  for (; e + 2 <= o1; e += 2) {
    int j0 = adj[e], j1 = adj[e + 1];
    unsigned u0 = h16[(size_t)j0 * 64 + lane];
    unsigned u1 = h16[(size_t)j1 * 64 + lane];
    ml[0] = fmaxf(ml[0], __uint_as_float(u0 << 16));
    mh[0] = fmaxf(mh[0], __uint_as_float(u0 & 0xFFFF0000u));
    ml[1] = fmaxf(ml[1], __uint_as_float(u1 << 16));
    mh[1] = fmaxf(mh[1], __uint_as_float(u1 & 0xFFFF0000u));
  }
  if (e < o1) {
    unsigned u0 = h16[(size_t)adj[e] * 64 + lane];
    ml[0] = fmaxf(ml[0], __uint_as_float(u0 << 16));
    mh[0] = fmaxf(mh[0], __uint_as_float(u0 & 0xFFFF0000u));
  }
  float mlo = fmaxf(fmaxf(ml[0], ml[1]), fmaxf(ml[2], ml[3]));
  float mhi = fmaxf(fmaxf(mh[0], mh[1]), fmaxf(mh[2], mh[3]));
  unsigned us = h16[(size_t)i * 64 + lane];
  float hx = __uint_as_float(us << 16);
  float hy = __uint_as_float(us & 0xFFFF0000u);
  float rx = (o1 > o0) ? (mlo - hx) : 0.f;
  float ry = (o1 > o0) ? (mhi - hy) : 0.f;
  aggr16[(size_t)i * 64 + lane] = bf16rne(rx) | (bf16rne(ry) << 16);
}

// out16 = bf16(relu([A1|A2] @ W + bias)) via bf16 MFMA, fp32 accumulate.
// Block: 128 rows x 128 cols, 8 waves (16-row stripe each), K=256 in 8 steps.
// One 64KB weight stage serves 128 rows (2x the old 64-row block: half the
// weight traffic, 512 threads -> 16 waves/CU at 2 blocks/CU = 50% occupancy).
// If out16 == nullptr: fused global-max-pool epilogue (sorted batch) instead.
__global__ __launch_bounds__(512) void k_gemm_mfma(
    const uint4* __restrict__ A1, const uint4* __restrict__ A2,
    const uint4* __restrict__ Wb, const float* __restrict__ bias,
    unsigned* __restrict__ out16, const int* __restrict__ batch,
    float* __restrict__ g, int N) {
  __shared__ uint4 Bs[4096];  // 64 KB; reused as Ct[128][132] ushort (33.8 KB)
  int t = threadIdx.x;
  int m0 = blockIdx.x * 128;
  for (int i = t; i < 4096; i += 512) Bs[i] = Wb[i];
  int wave = t >> 6, lane = t & 63;
  int kg = lane >> 4;
  int arow = m0 + wave * 16 + (lane & 15);
  int arc = min(arow, N - 1);
  const uint4* R1 = A1 + (size_t)arc * 16;
  const uint4* R2 = A2 + (size_t)arc * 16;
  f32x4 acc[8];
#pragma unroll
  for (int nf = 0; nf < 8; ++nf) acc[nf] = (f32x4){0.f, 0.f, 0.f, 0.f};
  __syncthreads();
#pragma unroll
  for (int ks = 0; ks < 8; ++ks) {
    UV a;
    a.u = (ks < 4) ? R1[ks * 4 + kg] : R2[(ks - 4) * 4 + kg];
#pragma unroll
    for (int nf = 0; nf < 8; ++nf) {
      UV b;
      b.u = Bs[(ks * 8 + nf) * 64 + lane];
      acc[nf] = __builtin_amdgcn_mfma_f32_16x16x32_bf16(a.s, b.s, acc[nf], 0, 0, 0);
    }
  }
  __syncthreads();
  unsigned short* Ct = (unsigned short*)Bs;  // [128][132]
#pragma unroll
  for (int nf = 0; nf < 8; ++nf) {
    float bc = bias[nf * 16 + (lane & 15)];
#pragma unroll
    for (int r = 0; r < 4; ++r) {
      int row = wave * 16 + kg * 4 + r;
      float v = fmaxf(acc[nf][r] + bc, 0.f);
      Ct[row * 132 + nf * 16 + (lane & 15)] = (unsigned short)bf16rne(v);
    }
  }
  __syncthreads();
  if (out16) {
    const unsigned* CtU = (const unsigned*)Bs;
    for (int i = t; i < 8192; i += 512) {
      int row = i >> 6, cp = i & 63;
      int gr = m0 + row;
      if (gr < N) out16[(size_t)gr * 64 + cp] = CtU[row * 66 + cp];
    }
  } else if (t < 128) {
    // fused max-pool over this block's 128 sorted-batch rows
    int f = t;
    int cur = -1;
    float m = 0.f;
    for (int r = 0; r < 128; ++r) {
      int gr = m0 + r;
      if (gr >= N) break;
      int bb = batch[gr];
      if (bb != cur) {
        if (cur >= 0) atomicMax((int*)&g[cur * FEAT + f], __float_as_int(m));
        cur = bb;
        m = 0.f;
      }
      unsigned u = (unsigned)Ct[r * 132 + f];
      m = fmaxf(m, __uint_as_float(u << 16));
    }
    if (cur >= 0) atomicMax((int*)&g[cur * FEAT + f], __float_as_int(m));
  }
}

__global__ __launch_bounds__(64) void k_mlp(
    const float* __restrict__ g, const float* __restrict__ Wf1,
    const float* __restrict__ bf1, const float* __restrict__ Wf2,
    const float* __restrict__ bf2, float* __restrict__ out) {
  __shared__ float gr[128];
  __shared__ float h1[64];
  int gi = blockIdx.x, t = threadIdx.x;
  gr[t] = g[gi * FEAT + t];
  gr[t + 64] = g[gi * FEAT + 64 + t];
  __syncthreads();
  float acc = bf1[t];
#pragma unroll 4
  for (int k = 0; k < 128; ++k) acc += gr[k] * Wf1[k * 64 + t];
  h1[t] = fmaxf(acc, 0.f);
  __syncthreads();
  float logit = -INFINITY;
  if (t < 40) {
    float a = bf2[t];
#pragma unroll 4
    for (int k = 0; k < 64; ++k) a += h1[k] * Wf2[k * 40 + t];
    logit = a;
  }
  float m = logit;
#pragma unroll
  for (int off = 32; off; off >>= 1) m = fmaxf(m, __shfl_xor(m, off));
  float e = (t < 40) ? expf(logit - m) : 0.f;
  float s = e;
#pragma unroll
  for (int off = 32; off; off >>= 1) s += __shfl_xor(s, off);
  if (t < 40) out[gi * 40 + t] = logit - m - logf(s);
}

extern "C" void kernel_launch(void* const* d_in, const int* in_sizes, int n_in,
                              void* d_out, int out_size, void* d_ws, size_t ws_size,
                              hipStream_t stream) {
  const float* x = (const float*)d_in[0];
  const int* ei = (const int*)d_in[1];
  const int* batch = (const int*)d_in[2];
  const float* W1 = (const float*)d_in[3];
  const float* b1 = (const float*)d_in[4];
  const float* W2 = (const float*)d_in[5];
  const float* b2 = (const float*)d_in[6];
  const float* W3 = (const float*)d_in[7];
  const float* b3 = (const float*)d_in[8];
  const float* Wf1 = (const float*)d_in[9];
  const float* bf1 = (const float*)d_in[10];
  const float* Wf2 = (const float*)d_in[11];
  const float* bf2 = (const float*)d_in[12];
  float* out = (float*)d_out;

  const int N = NODES;
  const int E = in_sizes[1] / 2;  // 800000 original edges
  const int* src = ei;
  const int* dst = ei + E;

  char* ws = (char*)d_ws;
  size_t off = 0;
  auto carve = [&](size_t bytes) {
    void* p = ws + off;
    off += (bytes + 255) & ~(size_t)255;
    return p;
  };
  unsigned* hA16 = (unsigned*)carve((size_t)N * 64 * 4);
  unsigned* hB16 = (unsigned*)carve((size_t)N * 64 * 4);
  unsigned* aggr16 = (unsigned*)carve((size_t)N * 64 * 4);  // binned aliases this
  uint4* Wb1 = (uint4*)carve(65536);
  uint4* Wb2 = (uint4*)carve(65536);
  uint4* Wb3 = (uint4*)carve(65536);
  int* zreg = (int*)carve((size_t)8704 * 4);  // bcount(256) | bcur(256) | g(8192)
  int* bcount = zreg;
  int* bcur = zreg + 256;
  float* g = (float*)(zreg + 512);
  int* bbase = (int*)carve((size_t)(NB + 1) * 4);
  int* offs8 = (int*)carve(((size_t)N * 8 + 1) * 4);
  int* adj = (int*)carve((size_t)2 * E * 4);
  uint2* binned = (uint2*)aggr16;  // 12.8 MB, dead until first k_nmax

  const int nEB = (E + 4095) / 4096;  // 196 edge-chunk blocks
  const int nMB = (N + 127) / 128;    // 391 GEMM blocks

  // ---- prep (cast + wpack + zero) and binned CSR build ----
  k_prep<<<12582, 256, 0, stream>>>(x, W1, W2, W3, hA16, Wb1, Wb2, Wb3, zreg);
  k_bcount<<<nEB, 256, 0, stream>>>(src, dst, E, bcount);
  k_bscan<<<1, 256, 0, stream>>>(bcount, bbase, 2 * E);
  k_bin<<<nEB, 256, 0, stream>>>(src, dst, E, bbase, bcur, binned);
  k_build<<<NB, 256, 0, stream>>>(bbase, binned, offs8, adj, N, 2 * E);

  // ---- 3x MRConv (bf16 gather-max, bf16 MFMA concat-GEMM) ----
  k_nmax<<<N / 4, 256, 0, stream>>>(hA16, offs8, adj, aggr16);
  k_gemm_mfma<<<nMB, 512, 0, stream>>>((const uint4*)hA16, (const uint4*)aggr16,
                                       Wb1, b1, hB16, batch, g, N);
  k_nmax<<<N / 4, 256, 0, stream>>>(hB16, offs8, adj, aggr16);
  k_gemm_mfma<<<nMB, 512, 0, stream>>>((const uint4*)hB16, (const uint4*)aggr16,
                                       Wb2, b2, hA16, batch, g, N);
  k_nmax<<<N / 4, 256, 0, stream>>>(hA16, offs8, adj, aggr16);
  k_gemm_mfma<<<nMB, 512, 0, stream>>>((const uint4*)hA16, (const uint4*)aggr16,
                                       Wb3, b3, (unsigned*)nullptr, batch, g, N);

  // ---- MLP head + log_softmax (pool fused into last GEMM) ----
  k_mlp<<<64, 64, 0, stream>>>(g, Wf1, bf1, Wf2, bf2, out);
}